// Round 1
// baseline (1881.015 us; speedup 1.0000x reference)
//
#include <hip/hip_runtime.h>
#include <math.h>

// Problem constants
constexpr int NB = 32, HH = 32, WW = 32, CD = 256, NK = 4096;
constexpr int T_ = NB * WW * HH;                       // 32768 tokens
constexpr long long NQ = (long long)NB * CD * HH * WW; // 8388608
constexpr long long OFF_LOSS = NQ;
constexpr long long OFF_PERP = NQ + 1;
constexpr long long OFF_ENC  = NQ + 2;                    // 8388610
constexpr long long ENC_SZ   = (long long)T_ * NK;        // 134217728
constexpr long long OFF_IDX  = OFF_ENC + ENC_SZ;          // 142606338
constexpr long long OFF_DIST = OFF_IDX + T_;              // 142639106
// scratch inside encodings output region (dead before its memset)
constexpr long long SCR_FLAT = OFF_ENC + 2;               // 8388612 (16B-aligned)
constexpr long long SCR_PVAL = SCR_FLAT + (long long)T_ * CD;  // 16777220
constexpr long long SCR_PIDX = SCR_PVAL + (long long)T_ * 32;  // 17825796

#define TID ((int)threadIdx.x)

// ---- NCHW -> [T, C] transpose (both sides coalesced via LDS) ----
__global__ __launch_bounds__(256) void k_transpose(const float* __restrict__ in,
                                                   float* __restrict__ flat) {
  __shared__ float t[256][33];  // +1 pad: phase-2 column reads conflict-free
  int b = blockIdx.x, n = b >> 5, h = b & 31;
  int w = TID & 31, c8 = TID >> 5;
  const float* src = in + (long long)n * 262144 + h * 32;  // + c*1024 + w
#pragma unroll
  for (int p = 0; p < 32; ++p) {
    int c = p * 8 + c8;
    t[c][w] = src[c * 1024 + w];
  }
  __syncthreads();
  float* dst = flat + ((long long)n * 1024 + h) * 256;     // + w*8192 + c
#pragma unroll
  for (int w2 = 0; w2 < 32; ++w2) dst[w2 * 8192 + TID] = t[TID][w2];
}

// ---- per-row squared L2 norm (one wave per row) ----
__global__ __launch_bounds__(256) void k_rowsq(const float* __restrict__ src,
                                               float* __restrict__ dst, int nrows) {
  int row = blockIdx.x * 4 + (TID >> 6);
  if (row >= nrows) return;
  int lane = TID & 63;
  float4 v = *(const float4*)(src + (long long)row * 256 + lane * 4);
  float s = v.x * v.x + v.y * v.y + v.z * v.z + v.w * v.w;
#pragma unroll
  for (int o = 32; o; o >>= 1) s += __shfl_down(s, o);
  if (lane == 0) dst[row] = s;
}

// ---- fp32 distance GEMM: 128x128 tile, BK=16, 8x8 micro-tile, fused argmin ----
__global__ __launch_bounds__(256) void k_gemm(const float* __restrict__ A,
                                              const float* __restrict__ B,
                                              const float* __restrict__ xsq,
                                              const float* __restrict__ esq,
                                              float* __restrict__ dist,
                                              float* __restrict__ pval,
                                              int* __restrict__ pidx) {
  __shared__ float As[16][132];  // [k][m], pad 4 -> 2-way (free) staging writes
  __shared__ float Bs[16][132];
  int tid = TID;
  int bm = blockIdx.x >> 5, bn = blockIdx.x & 31;
  int tn = tid & 15, tm = tid >> 4;
  int lr = tid >> 2, lk = tid & 3;
  const float* Ag = A + (long long)bm * 128 * 256 + lr * 256 + lk * 4;
  const float* Bg = B + (long long)bn * 128 * 256 + lr * 256 + lk * 4;

  float acc[2][4][2][4] = {};
  for (int kt = 0; kt < 16; ++kt) {
    float4 a0 = *(const float4*)(Ag + kt * 16);
    float4 a1 = *(const float4*)(Ag + 64 * 256 + kt * 16);
    float4 b0 = *(const float4*)(Bg + kt * 16);
    float4 b1 = *(const float4*)(Bg + 64 * 256 + kt * 16);
    __syncthreads();  // previous-iteration LDS reads done
    As[lk * 4 + 0][lr] = a0.x; As[lk * 4 + 1][lr] = a0.y;
    As[lk * 4 + 2][lr] = a0.z; As[lk * 4 + 3][lr] = a0.w;
    As[lk * 4 + 0][lr + 64] = a1.x; As[lk * 4 + 1][lr + 64] = a1.y;
    As[lk * 4 + 2][lr + 64] = a1.z; As[lk * 4 + 3][lr + 64] = a1.w;
    Bs[lk * 4 + 0][lr] = b0.x; Bs[lk * 4 + 1][lr] = b0.y;
    Bs[lk * 4 + 2][lr] = b0.z; Bs[lk * 4 + 3][lr] = b0.w;
    Bs[lk * 4 + 0][lr + 64] = b1.x; Bs[lk * 4 + 1][lr + 64] = b1.y;
    Bs[lk * 4 + 2][lr + 64] = b1.z; Bs[lk * 4 + 3][lr + 64] = b1.w;
    __syncthreads();
#pragma unroll
    for (int kk = 0; kk < 16; ++kk) {
      float4 av0 = *(const float4*)&As[kk][tm * 4];
      float4 av1 = *(const float4*)&As[kk][64 + tm * 4];
      float4 bv0 = *(const float4*)&Bs[kk][tn * 4];
      float4 bv1 = *(const float4*)&Bs[kk][64 + tn * 4];
      const float* ap0 = &av0.x; const float* ap1 = &av1.x;
      const float* bp0 = &bv0.x; const float* bp1 = &bv1.x;
#pragma unroll
      for (int i = 0; i < 4; ++i)
#pragma unroll
        for (int j = 0; j < 4; ++j) {
          acc[0][i][0][j] = fmaf(ap0[i], bp0[j], acc[0][i][0][j]);
          acc[0][i][1][j] = fmaf(ap0[i], bp1[j], acc[0][i][1][j]);
          acc[1][i][0][j] = fmaf(ap1[i], bp0[j], acc[1][i][0][j]);
          acc[1][i][1][j] = fmaf(ap1[i], bp1[j], acc[1][i][1][j]);
        }
    }
  }
  // epilogue: d = ||x||^2 - 2 x.e + ||e||^2, store + per-row argmin partial
  float4 es0 = *(const float4*)(esq + bn * 128 + tn * 4);
  float4 es1 = *(const float4*)(esq + bn * 128 + 64 + tn * 4);
  const float* ep0 = &es0.x; const float* ep1 = &es1.x;
#pragma unroll
  for (int hh = 0; hh < 2; ++hh)
#pragma unroll
    for (int i = 0; i < 4; ++i) {
      int row = bm * 128 + hh * 64 + tm * 4 + i;
      float xs = xsq[row];
      float dv[8];
#pragma unroll
      for (int j = 0; j < 4; ++j) {
        dv[j]     = xs - 2.0f * acc[hh][i][0][j] + ep0[j];
        dv[4 + j] = xs - 2.0f * acc[hh][i][1][j] + ep1[j];
      }
      float bv = 3.4e38f; int bc = 0;
#pragma unroll
      for (int g = 0; g < 2; ++g)
#pragma unroll
        for (int j = 0; j < 4; ++j) {   // ascending col order => ties keep lowest idx
          float v = dv[g * 4 + j];
          int c = g * 64 + tn * 4 + j;
          if (v < bv) { bv = v; bc = c; }
        }
      float* drow = dist + (long long)row * 4096 + bn * 128;
      *(float2*)(drow + tn * 4)          = make_float2(dv[0], dv[1]);
      *(float2*)(drow + tn * 4 + 2)      = make_float2(dv[2], dv[3]);
      *(float2*)(drow + 64 + tn * 4)     = make_float2(dv[4], dv[5]);
      *(float2*)(drow + 64 + tn * 4 + 2) = make_float2(dv[6], dv[7]);
#pragma unroll
      for (int m = 1; m < 16; m <<= 1) {  // reduce across tn lanes (same rows)
        float ov = __shfl_xor(bv, m);
        int oc = __shfl_xor(bc, m);
        if (ov < bv || (ov == bv && oc < bc)) { bv = ov; bc = oc; }
      }
      if (tn == 0) {
        pval[(long long)row * 32 + bn] = bv;
        pidx[(long long)row * 32 + bn] = bn * 128 + bc;
      }
    }
}

// ---- final argmin over 32 column-block partials; indices + histogram ----
__global__ __launch_bounds__(256) void k_argmin(const float* __restrict__ pval,
                                                const int* __restrict__ pidx,
                                                int* __restrict__ idxArr,
                                                float* __restrict__ outIdx,
                                                int* __restrict__ hist) {
  int t = blockIdx.x * 256 + TID;
  float bv = 3.4e38f; int bc = 0;
#pragma unroll
  for (int b = 0; b < 32; ++b) {  // ascending col blocks => strict < keeps lowest idx
    float v = pval[(long long)t * 32 + b];
    if (v < bv) { bv = v; bc = pidx[(long long)t * 32 + b]; }
  }
  idxArr[t] = bc;
  outIdx[t] = (float)bc;
  atomicAdd(&hist[bc], 1);
}

// ---- one-hot scatter (encodings pre-zeroed by memset) ----
__global__ __launch_bounds__(256) void k_scatter(const int* __restrict__ idxArr,
                                                 float* __restrict__ enc) {
  int t = blockIdx.x * 256 + TID;
  enc[(long long)t * 4096 + idxArr[t]] = 1.0f;
}

// ---- quantized gather -> NCHW output + loss partial ----
__global__ __launch_bounds__(256) void k_quant(const float* __restrict__ in,
                                               const float* __restrict__ emb,
                                               const int* __restrict__ idxArr,
                                               float* __restrict__ outQ,
                                               float* __restrict__ lossAcc) {
  __shared__ float q[32][257];
  __shared__ float ls[4];
  int b = blockIdx.x, n = b >> 5, h = b & 31;
  for (int w = 0; w < 32; ++w) {
    int id = idxArr[(n * 32 + w) * 32 + h];
    q[w][TID] = emb[(long long)id * 256 + TID];
  }
  __syncthreads();
  float sum = 0.f;
  int w = TID & 31, c8 = TID >> 5;
  const float* xin = in + (long long)n * 262144 + h * 32;
  float* xout = outQ + (long long)n * 262144 + h * 32;
#pragma unroll
  for (int p = 0; p < 32; ++p) {
    int c = p * 8 + c8;
    float qa = q[w][c];
    float xv = xin[c * 1024 + w];
    float d = qa - xv;
    sum += d * d;
    xout[c * 1024 + w] = qa;
  }
#pragma unroll
  for (int o = 32; o; o >>= 1) sum += __shfl_down(sum, o);
  if ((TID & 63) == 0) ls[TID >> 6] = sum;
  __syncthreads();
  if (TID == 0) atomicAdd(lossAcc, ls[0] + ls[1] + ls[2] + ls[3]);
}

// ---- loss + perplexity ----
__global__ __launch_bounds__(256) void k_final(const int* __restrict__ hist,
                                               const float* __restrict__ lossAcc,
                                               float* __restrict__ outLoss,
                                               float* __restrict__ outPerp) {
  __shared__ float ls[4];
  float s = 0.f;
  for (int k = TID; k < 4096; k += 256) {
    float p = (float)hist[k] * (1.0f / 32768.0f);
    s += p * logf(p + 1e-10f);
  }
#pragma unroll
  for (int o = 32; o; o >>= 1) s += __shfl_down(s, o);
  if ((TID & 63) == 0) ls[TID >> 6] = s;
  __syncthreads();
  if (TID == 0) {
    // forward value: q_latent_loss == e_latent_loss == mean((q-x)^2)
    *outLoss = lossAcc[0] * (1.25f / 8388608.0f);
    *outPerp = expf(-(ls[0] + ls[1] + ls[2] + ls[3]));
  }
}

extern "C" void kernel_launch(void* const* d_in, const int* in_sizes, int n_in,
                              void* d_out, int out_size, void* d_ws, size_t ws_size,
                              hipStream_t stream) {
  const float* inputs = (const float*)d_in[0];
  const float* emb = (const float*)d_in[1];
  float* out = (float*)d_out;
  float* ws = (float*)d_ws;

  // ws layout (floats): [0] lossAcc, [64..] hist(4096 int), [8192..] xsq(32768),
  // [40960..] esq(4096), [45056..] idxArr(32768 int)  => ~311 KB
  float* lossAcc = ws;
  int* hist = (int*)(ws + 64);
  float* xsq = ws + 8192;
  float* esq = ws + 40960;
  int* idxArr = (int*)(ws + 45056);

  float* flat = out + SCR_FLAT;            // scratch in encodings region
  float* pval = out + SCR_PVAL;
  int* pidx = (int*)(out + SCR_PIDX);
  float* dist = out + OFF_DIST;
  float* enc = out + OFF_ENC;

  hipMemsetAsync(d_ws, 0, 8192 * 4, stream);            // lossAcc + hist
  k_transpose<<<1024, 256, 0, stream>>>(inputs, flat);
  k_rowsq<<<8192, 256, 0, stream>>>(flat, xsq, 32768);
  k_rowsq<<<1024, 256, 0, stream>>>(emb, esq, 4096);
  k_gemm<<<8192, 256, 0, stream>>>(flat, emb, xsq, esq, dist, pval, pidx);
  k_argmin<<<128, 256, 0, stream>>>(pval, pidx, idxArr, out + OFF_IDX, hist);
  hipMemsetAsync(enc, 0, (size_t)ENC_SZ * 4, stream);   // zero one-hot (kills scratch)
  k_scatter<<<128, 256, 0, stream>>>(idxArr, enc);
  k_quant<<<1024, 256, 0, stream>>>(inputs, emb, idxArr, out, lossAcc);
  k_final<<<1, 256, 0, stream>>>(hist, lossAcc, out + OFF_LOSS, out + OFF_PERP);
}